// Round 1
// baseline (567.785 us; speedup 1.0000x reference)
//
#include <hip/hip_runtime.h>

#define NNODE 100
#define HDIM  128
#define NEDGE 360
#define LDSH  136      // padded bf16 row: 272 B = 16B-aligned rows, 4-word bank stagger
#define NTHREADS 512
#define CLSMAX 96
#define HSTRIDE 132    // fp32 h-buffer row stride (528 B)

typedef float f32x4 __attribute__((ext_vector_type(4)));
typedef short s16x8 __attribute__((ext_vector_type(8)));

__device__ __forceinline__ float bf2f(short s) {
  union { unsigned int u; float f; } v;
  v.u = ((unsigned int)(unsigned short)s) << 16;
  return v.f;
}
__device__ __forceinline__ short f2bf(float f) {  // RNE
  union { float f; unsigned int u; } v; v.f = f;
  unsigned int u = v.u + 0x7fffu + ((v.u >> 16) & 1u);
  return (short)(u >> 16);
}

// Load a 128x128 fp32 weight (row-major [k][n]) into LDS transposed bf16 [n][k]
__device__ __forceinline__ void load_wt(short* wt, const float* __restrict__ W, int tid) {
#pragma unroll
  for (int it = 0; it < (HDIM * HDIM / 4) / NTHREADS; ++it) {  // 8 iters
    int idx = tid + it * NTHREADS;
    float4 w = ((const float4*)W)[idx];
    int k = (idx * 4) >> 7;
    int n = (idx * 4) & 127;
    wt[(n + 0) * LDSH + k] = f2bf(w.x);
    wt[(n + 1) * LDSH + k] = f2bf(w.y);
    wt[(n + 2) * LDSH + k] = f2bf(w.z);
    wt[(n + 3) * LDSH + k] = f2bf(w.w);
  }
}

__global__ __launch_bounds__(NTHREADS)
void mpnn_fused_kernel(const float* __restrict__ x,
                       const int* __restrict__ src_idx,
                       const int* __restrict__ dst_idx,
                       const float* __restrict__ edge_dir,
                       const float* __restrict__ w_msg1, const float* __restrict__ b_msg1,
                       const float* __restrict__ w_msg2, const float* __restrict__ b_msg2,
                       const float* __restrict__ w_upd1, const float* __restrict__ b_upd1,
                       const float* __restrict__ w_upd2, const float* __restrict__ b_upd2,
                       const float* __restrict__ gamma, const float* __restrict__ beta,
                       float* __restrict__ out)
{
  // LDS carve. hbf (fp32 LN buffer, 100x132 = 52,800 B) aliases wt1+wt2 (69,632 B)
  // and is only written after a barrier that ends all wt1 reads.
  __shared__ __align__(16) char smem[151232];
  short* wt1 = (short*)(smem);            // [128][LDSH] bf16, transposed weight
  short* wt2 = (short*)(smem + 34816);    // [128][LDSH]
  short* xls = (short*)(smem + 69632);    // [100][LDSH] x in bf16
  short* agg = (short*)(smem + 96832);    // [100][LDSH] aggregated messages, bf16
  short* mbf = (short*)(smem + 124032);   // [100][LDSH] m / u1 intermediate, bf16
  float* hbf = (float*)(smem);            // [100][HSTRIDE] fp32 (aliases wt1/wt2)
  __shared__ float b1s[HDIM], w1ls[HDIM], b2s[HDIM], bu1s[HDIM], bu2s[HDIM],
                   gms[HDIM], bts[HDIM];
  __shared__ int cls_src[4][CLSMAX], cls_dst[4][CLSMAX], cls_cnt[4];

  const int tid  = threadIdx.x;
  const int lane = tid & 63;
  const int wave = tid >> 6;      // 0..7
  const int quad = lane >> 4;     // 0..3
  const int l16  = lane & 15;
  const int wr   = wave >> 2;     // 0..1  row split
  const int wc   = wave & 3;      // 0..3  col split (2 col-tiles of 16 each)
  const int b    = blockIdx.x;
  const float* xb = x + (size_t)b * (NNODE * HDIM);

  // ---------------- setup ----------------
  if (tid < 4) cls_cnt[tid] = 0;
  for (int i = tid; i < 4 * CLSMAX; i += NTHREADS) {
    ((int*)cls_src)[i] = 0; ((int*)cls_dst)[i] = 0;
  }
  for (int i = tid; i < NNODE * LDSH; i += NTHREADS) agg[i] = 0;
  if (tid < HDIM) {
    b1s[tid]  = b_msg1[tid];
    w1ls[tid] = w_msg1[HDIM * HDIM + tid];  // row 128 of (129,128)
    b2s[tid]  = b_msg2[tid];
    bu1s[tid] = b_upd1[tid];
    bu2s[tid] = b_upd2[tid];
    gms[tid]  = gamma[tid];
    bts[tid]  = beta[tid];
  }
  __syncthreads();
  // classify edges by direction (each class has all-distinct dst -> race-free scatter)
  if (tid < NEDGE) {
    int d = (int)(edge_dir[tid] * 3.0f + 0.5f);
    int p = atomicAdd(&cls_cnt[d], 1);
    cls_src[d][p] = src_idx[tid];
    cls_dst[d][p] = dst_idx[tid];
  }
  // stage x -> LDS bf16
  for (int i = tid; i < (NNODE * HDIM) / 4; i += NTHREADS) {
    float4 v = ((const float4*)xb)[i];
    int r = (i * 4) >> 7, c = (i * 4) & 127;
    short* p = &xls[r * LDSH + c];
    p[0] = f2bf(v.x); p[1] = f2bf(v.y); p[2] = f2bf(v.z); p[3] = f2bf(v.w);
  }
  load_wt(wt1, w_msg1, tid);   // k rows 0..127 of w_msg1
  load_wt(wt2, w_msg2, tid);
  __syncthreads();

  // ---------------- phase A: messages per direction class ----------------
  for (int d = 0; d < 4; ++d) {
    const int cnt = cls_cnt[d];
    const float dsc = (float)d * (1.0f / 3.0f);

    // GEMM1: m = relu(x[src] @ W1 + b1 + (d/3)*w1_last), rows = edges of class
    {
      f32x4 acc[3][2] = {};
      int rows[3];
#pragma unroll
      for (int rt = 0; rt < 3; ++rt) rows[rt] = cls_src[d][wr * 48 + rt * 16 + l16];
#pragma unroll
      for (int kq = 0; kq < 4; ++kq) {
        const int ko = kq * 32 + quad * 8;
        s16x8 af[3], bf[2];
#pragma unroll
        for (int rt = 0; rt < 3; ++rt)
          af[rt] = *(const s16x8*)&xls[rows[rt] * LDSH + ko];
#pragma unroll
        for (int ct = 0; ct < 2; ++ct)
          bf[ct] = *(const s16x8*)&wt1[(wc * 32 + ct * 16 + l16) * LDSH + ko];
#pragma unroll
        for (int rt = 0; rt < 3; ++rt)
#pragma unroll
          for (int ct = 0; ct < 2; ++ct)
            acc[rt][ct] = __builtin_amdgcn_mfma_f32_16x16x32_bf16(af[rt], bf[ct], acc[rt][ct], 0, 0, 0);
      }
#pragma unroll
      for (int rt = 0; rt < 3; ++rt)
#pragma unroll
        for (int ct = 0; ct < 2; ++ct) {
          const int col = wc * 32 + ct * 16 + l16;
          const float ba = b1s[col] + dsc * w1ls[col];
#pragma unroll
          for (int i = 0; i < 4; ++i) {
            const int row = wr * 48 + rt * 16 + quad * 4 + i;  // <= 95
            float v = acc[rt][ct][i] + ba;
            mbf[row * LDSH + col] = f2bf(v > 0.f ? v : 0.f);
          }
        }
    }
    __syncthreads();

    // GEMM2: msg = m @ W2 + b2 ; scatter-add into agg[dst] (bf16 RMW, race-free in-class)
    {
      f32x4 acc[3][2] = {};
#pragma unroll
      for (int kq = 0; kq < 4; ++kq) {
        const int ko = kq * 32 + quad * 8;
        s16x8 af[3], bf[2];
#pragma unroll
        for (int rt = 0; rt < 3; ++rt)
          af[rt] = *(const s16x8*)&mbf[(wr * 48 + rt * 16 + l16) * LDSH + ko];
#pragma unroll
        for (int ct = 0; ct < 2; ++ct)
          bf[ct] = *(const s16x8*)&wt2[(wc * 32 + ct * 16 + l16) * LDSH + ko];
#pragma unroll
        for (int rt = 0; rt < 3; ++rt)
#pragma unroll
          for (int ct = 0; ct < 2; ++ct)
            acc[rt][ct] = __builtin_amdgcn_mfma_f32_16x16x32_bf16(af[rt], bf[ct], acc[rt][ct], 0, 0, 0);
      }
#pragma unroll
      for (int rt = 0; rt < 3; ++rt)
#pragma unroll
        for (int ct = 0; ct < 2; ++ct) {
          const int col = wc * 32 + ct * 16 + l16;
#pragma unroll
          for (int i = 0; i < 4; ++i) {
            const int e = wr * 48 + rt * 16 + quad * 4 + i;
            if (e < cnt) {
              const int dn = cls_dst[d][e];
              short* p = &agg[dn * LDSH + col];
              *p = f2bf(bf2f(*p) + acc[rt][ct][i] + b2s[col]);
            }
          }
        }
    }
    __syncthreads();
  }

  // ---------------- phase B: node update ----------------
  load_wt(wt1, w_upd1, tid);                 // K rows 0..127  (x part)
  load_wt(wt2, w_upd1 + HDIM * HDIM, tid);   // K rows 128..255 (agg part)
  __syncthreads();

  // B1: u1 = relu(x @ Wu1a + agg @ Wu1b + bu1), rows = nodes (tiles cover 0..127, guard >=100)
  {
    const int rbase = wr * 64;
    f32x4 acc[4][2] = {};
#pragma unroll
    for (int kq = 0; kq < 4; ++kq) {
      const int ko = kq * 32 + quad * 8;
      s16x8 ax[4], ag[4], bx[2], bg[2];
#pragma unroll
      for (int rt = 0; rt < 4; ++rt) {
        int m = rbase + rt * 16 + l16; if (m > NNODE - 1) m = NNODE - 1;
        ax[rt] = *(const s16x8*)&xls[m * LDSH + ko];
        ag[rt] = *(const s16x8*)&agg[m * LDSH + ko];
      }
#pragma unroll
      for (int ct = 0; ct < 2; ++ct) {
        const int n = (wc * 32 + ct * 16 + l16) * LDSH + ko;
        bx[ct] = *(const s16x8*)&wt1[n];
        bg[ct] = *(const s16x8*)&wt2[n];
      }
#pragma unroll
      for (int rt = 0; rt < 4; ++rt)
#pragma unroll
        for (int ct = 0; ct < 2; ++ct) {
          acc[rt][ct] = __builtin_amdgcn_mfma_f32_16x16x32_bf16(ax[rt], bx[ct], acc[rt][ct], 0, 0, 0);
          acc[rt][ct] = __builtin_amdgcn_mfma_f32_16x16x32_bf16(ag[rt], bg[ct], acc[rt][ct], 0, 0, 0);
        }
    }
#pragma unroll
    for (int rt = 0; rt < 4; ++rt)
#pragma unroll
      for (int ct = 0; ct < 2; ++ct) {
        const int col = wc * 32 + ct * 16 + l16;
#pragma unroll
        for (int i = 0; i < 4; ++i) {
          const int row = rbase + rt * 16 + quad * 4 + i;
          if (row < NNODE) {
            float v = acc[rt][ct][i] + bu1s[col];
            mbf[row * LDSH + col] = f2bf(v > 0.f ? v : 0.f);
          }
        }
      }
  }
  __syncthreads();
  load_wt(wt1, w_upd2, tid);
  __syncthreads();

  // B2: u = u1 @ Wu2 + bu2 ; h = x + u  -> hbf (aliases wt1/wt2 after barrier)
  {
    const int rbase = wr * 64;
    f32x4 acc[4][2] = {};
#pragma unroll
    for (int kq = 0; kq < 4; ++kq) {
      const int ko = kq * 32 + quad * 8;
      s16x8 au[4], bw[2];
#pragma unroll
      for (int rt = 0; rt < 4; ++rt) {
        int m = rbase + rt * 16 + l16; if (m > NNODE - 1) m = NNODE - 1;
        au[rt] = *(const s16x8*)&mbf[m * LDSH + ko];
      }
#pragma unroll
      for (int ct = 0; ct < 2; ++ct)
        bw[ct] = *(const s16x8*)&wt1[(wc * 32 + ct * 16 + l16) * LDSH + ko];
#pragma unroll
      for (int rt = 0; rt < 4; ++rt)
#pragma unroll
        for (int ct = 0; ct < 2; ++ct)
          acc[rt][ct] = __builtin_amdgcn_mfma_f32_16x16x32_bf16(au[rt], bw[ct], acc[rt][ct], 0, 0, 0);
    }
    __syncthreads();   // all waves done reading wt1 before hbf overwrites it
#pragma unroll
    for (int rt = 0; rt < 4; ++rt)
#pragma unroll
      for (int ct = 0; ct < 2; ++ct) {
        const int col = wc * 32 + ct * 16 + l16;
#pragma unroll
        for (int i = 0; i < 4; ++i) {
          const int row = rbase + rt * 16 + quad * 4 + i;
          if (row < NNODE)
            hbf[row * HSTRIDE + col] = acc[rt][ct][i] + bu2s[col] + xb[row * HDIM + col];
        }
      }
  }
  __syncthreads();

  // ---------------- phase C: LayerNorm ----------------
  for (int row = wave; row < NNODE; row += 8) {
    float2 v = *(const float2*)&hbf[row * HSTRIDE + lane * 2];
    float s1 = v.x + v.y;
    float s2 = v.x * v.x + v.y * v.y;
#pragma unroll
    for (int off = 32; off > 0; off >>= 1) {
      s1 += __shfl_xor(s1, off, 64);
      s2 += __shfl_xor(s2, off, 64);
    }
    const float mu = s1 * (1.0f / HDIM);
    float var = s2 * (1.0f / HDIM) - mu * mu;
    const float rs = rsqrtf(var + 1e-5f);
    const int c = lane * 2;
    float2 o;
    o.x = (v.x - mu) * rs * gms[c]     + bts[c];
    o.y = (v.y - mu) * rs * gms[c + 1] + bts[c + 1];
    *(float2*)&out[((size_t)b * NNODE + row) * HDIM + c] = o;
  }
}

extern "C" void kernel_launch(void* const* d_in, const int* in_sizes, int n_in,
                              void* d_out, int out_size, void* d_ws, size_t ws_size,
                              hipStream_t stream) {
  const float* x      = (const float*)d_in[0];
  const int*   src    = (const int*)  d_in[1];
  const int*   dst    = (const int*)  d_in[2];
  const float* ed     = (const float*)d_in[3];
  const float* w_msg1 = (const float*)d_in[4];
  const float* b_msg1 = (const float*)d_in[5];
  const float* w_msg2 = (const float*)d_in[6];
  const float* b_msg2 = (const float*)d_in[7];
  const float* w_upd1 = (const float*)d_in[8];
  const float* b_upd1 = (const float*)d_in[9];
  const float* w_upd2 = (const float*)d_in[10];
  const float* b_upd2 = (const float*)d_in[11];
  const float* gamma  = (const float*)d_in[12];
  const float* beta   = (const float*)d_in[13];
  float* out = (float*)d_out;

  const int Bsz = in_sizes[0] / (NNODE * HDIM);   // 2048
  mpnn_fused_kernel<<<Bsz, NTHREADS, 0, stream>>>(
      x, src, dst, ed, w_msg1, b_msg1, w_msg2, b_msg2,
      w_upd1, b_upd1, w_upd2, b_upd2, gamma, beta, out);
}

// Round 2
// 472.110 us; speedup vs baseline: 1.2027x; 1.2027x over previous
//
#include <hip/hip_runtime.h>

#define NNODE 100
#define HDIM  128
#define NEDGE 360
#define NT    512

typedef float f32x4 __attribute__((ext_vector_type(4)));
typedef short s16x8 __attribute__((ext_vector_type(8)));

__device__ __forceinline__ float bf2f(short s) {
  union { unsigned int u; float f; } v;
  v.u = ((unsigned int)(unsigned short)s) << 16;
  return v.f;
}
__device__ __forceinline__ short f2bf(float f) {  // RNE
  union { float f; unsigned int u; } v; v.f = f;
  unsigned int u = v.u + 0x7fffu + ((v.u >> 16) & 1u);
  return (short)(u >> 16);
}
// XOR-swizzled LDS index (shorts). Row stride 128 shorts (256B); 16B groups
// permuted by row&15 so stride-256B row accesses spread across all banks.
__device__ __forceinline__ int sidx(int r, int k) {
  return (r << 7) + ((((k >> 3) ^ (r & 15)) << 3) | (k & 7));
}

// ---------------- pre-kernel: weight convert/transpose + incoming-edge lists ----------------
// ws layout: [0 .. 5*32768) : 5 bf16 weight matrices, each [n][k] row-major (128x128)
//            m0=w_msg1(k<128), m1=w_msg2, m2=w_upd1[k<128], m3=w_upd1[k>=128], m4=w_upd2
//            [163840 .. 165440) : int inl[100][4], edge ids or -1
__global__ __launch_bounds__(NT)
void prep_kernel(const float* __restrict__ w_msg1, const float* __restrict__ w_msg2,
                 const float* __restrict__ w_upd1, const float* __restrict__ w_upd2,
                 const int* __restrict__ dst_idx,
                 short* __restrict__ wt, int* __restrict__ inl) {
  int idx = blockIdx.x * NT + threadIdx.x;
  if (idx < 5 * 16384) {
    int m = idx >> 14, i = idx & 16383;
    int n = i >> 7, k = i & 127;
    const float* W = (m == 0) ? w_msg1 : (m == 1) ? w_msg2 :
                     (m == 2) ? w_upd1 : (m == 3) ? (w_upd1 + 16384) : w_upd2;
    wt[idx] = f2bf(W[k * HDIM + n]);
  }
  if (blockIdx.x == 0) {
    __shared__ int cnt[NNODE];
    int tid = threadIdx.x;
    if (tid < NNODE) cnt[tid] = 0;
    __syncthreads();
    if (tid < NEDGE) {
      int d = dst_idx[tid];
      int p = atomicAdd(&cnt[d], 1);
      inl[d * 4 + p] = tid;
    }
    __syncthreads();
    if (tid < NNODE) {
      for (int p = cnt[tid]; p < 4; ++p) inl[tid * 4 + p] = -1;
    }
  }
}

// ---------------- main fused kernel: one block per batch element ----------------
__global__ __launch_bounds__(NT, 2)
void mpnn_main(const float* __restrict__ x,
               const int* __restrict__ src_idx,
               const float* __restrict__ edge_dir,
               const float* __restrict__ w_msg1,  // for last row (edge-feature column)
               const float* __restrict__ b_msg1, const float* __restrict__ b_msg2,
               const float* __restrict__ b_upd1, const float* __restrict__ b_upd2,
               const float* __restrict__ gamma, const float* __restrict__ beta,
               const short* __restrict__ wt, const int* __restrict__ inl_g,
               float* __restrict__ out)
{
  __shared__ __align__(16) char smem[157760];
  short* xls  = (short*)smem;                       // 100x(256B) = 25600
  short* msgr = (short*)(smem + 25600);             // 384x(256B) = 98304  (m / msg; later mbf+hbf)
  short* mbf  = msgr;                               // rows 0..127 (32768 B)
  float* hbf  = (float*)(smem + 25600 + 32768);     // 100x132 f32 = 52800 (within msgr region)
  short* agg  = (short*)(smem + 123904);            // 25600
  float* eds  = (float*)(smem + 149504);            // 384 f32
  int*   srcl = (int*)(smem + 151040);              // 384 i32
  int*   inls = (int*)(smem + 152576);              // 100 int4
  float* b1s  = (float*)(smem + 154176);
  float* w1ls = b1s + 128;
  float* b2s  = b1s + 256;
  float* bu1s = b1s + 384;
  float* bu2s = b1s + 512;
  float* gms  = b1s + 640;
  float* bts  = b1s + 768;

  const int tid  = threadIdx.x;
  const int lane = tid & 63;
  const int wave = tid >> 6;
  const int quad = lane >> 4;
  const int l16  = lane & 15;
  const int wr   = wave >> 1;   // 0..3  row group
  const int wc   = wave & 1;    // 0..1  col half (64 cols)
  const int b    = blockIdx.x;
  const float* xb = x + (size_t)b * (NNODE * HDIM);

  s16x8 wf[4][4];   // B-fragments [ct][kq], held in registers
  auto loadB = [&](const short* w) {
#pragma unroll
    for (int ct = 0; ct < 4; ++ct)
#pragma unroll
      for (int kq = 0; kq < 4; ++kq)
        wf[ct][kq] = *(const s16x8*)&w[(wc * 64 + ct * 16 + l16) * HDIM + kq * 32 + quad * 8];
  };

  // ---- staging ----
  loadB(wt);   // w_msg1 frags; global latency overlaps staging below
  for (int G = tid; G < NNODE * 16; G += NT) {
    int r = G >> 4, g = G & 15;
    const float4* p = (const float4*)(xb + r * HDIM + g * 8);
    float4 v0 = p[0], v1 = p[1];
    s16x8 h;
    h[0] = f2bf(v0.x); h[1] = f2bf(v0.y); h[2] = f2bf(v0.z); h[3] = f2bf(v0.w);
    h[4] = f2bf(v1.x); h[5] = f2bf(v1.y); h[6] = f2bf(v1.z); h[7] = f2bf(v1.w);
    *(s16x8*)&xls[sidx(r, g * 8)] = h;
  }
  if (tid < 384) {
    srcl[tid] = (tid < NEDGE) ? src_idx[tid] : 0;
    eds[tid]  = (tid < NEDGE) ? edge_dir[tid] : 0.f;
  }
  if (tid < NNODE) ((int4*)inls)[tid] = ((const int4*)inl_g)[tid];
  if (tid < HDIM) {
    b1s[tid]  = b_msg1[tid];
    w1ls[tid] = w_msg1[16384 + tid];
    b2s[tid]  = b_msg2[tid];
    bu1s[tid] = b_upd1[tid];
    bu2s[tid] = b_upd2[tid];
    gms[tid]  = gamma[tid];
    bts[tid]  = beta[tid];
  }
  __syncthreads();

  // ---- phase A, GEMM1: m[e] = relu(x[src[e]] @ W1 + b1 + ed[e]*w1_last), all 384 rows in 2 chunks ----
#pragma unroll
  for (int c = 0; c < 2; ++c) {
    f32x4 accA[3][4] = {};
    int rows[3];
#pragma unroll
    for (int rt = 0; rt < 3; ++rt) rows[rt] = srcl[c * 192 + wr * 48 + rt * 16 + l16];
#pragma unroll
    for (int kq = 0; kq < 4; ++kq) {
      const int ko = kq * 32 + quad * 8;
      s16x8 a[3];
#pragma unroll
      for (int rt = 0; rt < 3; ++rt) a[rt] = *(const s16x8*)&xls[sidx(rows[rt], ko)];
#pragma unroll
      for (int rt = 0; rt < 3; ++rt)
#pragma unroll
        for (int ct = 0; ct < 4; ++ct)
          accA[rt][ct] = __builtin_amdgcn_mfma_f32_16x16x32_bf16(a[rt], wf[ct][kq], accA[rt][ct], 0, 0, 0);
    }
#pragma unroll
    for (int rt = 0; rt < 3; ++rt)
#pragma unroll
      for (int i = 0; i < 4; ++i) {
        const int er = c * 192 + wr * 48 + rt * 16 + quad * 4 + i;
        const float ed = eds[er];
#pragma unroll
        for (int ct = 0; ct < 4; ++ct) {
          const int col = wc * 64 + ct * 16 + l16;
          float v = accA[rt][ct][i] + b1s[col] + ed * w1ls[col];
          msgr[sidx(er, col)] = f2bf(v > 0.f ? v : 0.f);
        }
      }
  }
  loadB(wt + 16384);   // w_msg2
  __syncthreads();     // m fully written

  // ---- phase A, GEMM2: msg[e] = m[e] @ W2 + b2, in-place over m ----
  {
    f32x4 acc0[3][4] = {};
#pragma unroll
    for (int kq = 0; kq < 4; ++kq) {
      const int ko = kq * 32 + quad * 8;
      s16x8 a[3];
#pragma unroll
      for (int rt = 0; rt < 3; ++rt) a[rt] = *(const s16x8*)&msgr[sidx(wr * 48 + rt * 16 + l16, ko)];
#pragma unroll
      for (int rt = 0; rt < 3; ++rt)
#pragma unroll
        for (int ct = 0; ct < 4; ++ct)
          acc0[rt][ct] = __builtin_amdgcn_mfma_f32_16x16x32_bf16(a[rt], wf[ct][kq], acc0[rt][ct], 0, 0, 0);
    }
    __syncthreads();   // all reads of chunk-0 m done
#pragma unroll
    for (int rt = 0; rt < 3; ++rt)
#pragma unroll
      for (int i = 0; i < 4; ++i) {
        const int er = wr * 48 + rt * 16 + quad * 4 + i;
#pragma unroll
        for (int ct = 0; ct < 4; ++ct) {
          const int col = wc * 64 + ct * 16 + l16;
          msgr[sidx(er, col)] = f2bf(acc0[rt][ct][i] + b2s[col]);
        }
      }
    f32x4 acc1[3][4] = {};
#pragma unroll
    for (int kq = 0; kq < 4; ++kq) {
      const int ko = kq * 32 + quad * 8;
      s16x8 a[3];
#pragma unroll
      for (int rt = 0; rt < 3; ++rt) a[rt] = *(const s16x8*)&msgr[sidx(192 + wr * 48 + rt * 16 + l16, ko)];
#pragma unroll
      for (int rt = 0; rt < 3; ++rt)
#pragma unroll
        for (int ct = 0; ct < 4; ++ct)
          acc1[rt][ct] = __builtin_amdgcn_mfma_f32_16x16x32_bf16(a[rt], wf[ct][kq], acc1[rt][ct], 0, 0, 0);
    }
    __syncthreads();   // all reads of chunk-1 m done
#pragma unroll
    for (int rt = 0; rt < 3; ++rt)
#pragma unroll
      for (int i = 0; i < 4; ++i) {
        const int er = 192 + wr * 48 + rt * 16 + quad * 4 + i;
#pragma unroll
        for (int ct = 0; ct < 4; ++ct) {
          const int col = wc * 64 + ct * 16 + l16;
          msgr[sidx(er, col)] = f2bf(acc1[rt][ct][i] + b2s[col]);
        }
      }
  }
  loadB(wt + 2 * 16384);   // w_upd1 (x half); latency overlaps agg gather
  __syncthreads();         // msg complete

  // ---- aggregate: agg[n] = sum of msg over incoming edges (<=4, distinct) ----
  for (int G = tid; G < NNODE * 16; G += NT) {
    int r = G >> 4, ko = (G & 15) * 8;
    int4 il = ((int4*)inls)[r];
    float s[8] = {0, 0, 0, 0, 0, 0, 0, 0};
    int es[4] = {il.x, il.y, il.z, il.w};
#pragma unroll
    for (int j = 0; j < 4; ++j) {
      if (es[j] >= 0) {
        s16x8 v = *(const s16x8*)&msgr[sidx(es[j], ko)];
#pragma unroll
        for (int t = 0; t < 8; ++t) s[t] += bf2f(v[t]);
      }
    }
    s16x8 o;
#pragma unroll
    for (int t = 0; t < 8; ++t) o[t] = f2bf(s[t]);
    *(s16x8*)&agg[sidx(r, ko)] = o;
  }
  __syncthreads();

  // ---- B1: u1 = relu(x @ Wu1a + agg @ Wu1b + bu1) -> mbf (rows 0..127) ----
  {
    f32x4 accB[2][4] = {};
#pragma unroll
    for (int kq = 0; kq < 4; ++kq) {
      const int ko = kq * 32 + quad * 8;
      s16x8 a0 = *(const s16x8*)&xls[sidx(wr * 32 + l16, ko)];
      s16x8 a1 = *(const s16x8*)&xls[sidx(wr * 32 + 16 + l16, ko)];
#pragma unroll
      for (int ct = 0; ct < 4; ++ct) {
        accB[0][ct] = __builtin_amdgcn_mfma_f32_16x16x32_bf16(a0, wf[ct][kq], accB[0][ct], 0, 0, 0);
        accB[1][ct] = __builtin_amdgcn_mfma_f32_16x16x32_bf16(a1, wf[ct][kq], accB[1][ct], 0, 0, 0);
      }
    }
    loadB(wt + 3 * 16384);   // w_upd1 (agg half)
#pragma unroll
    for (int kq = 0; kq < 4; ++kq) {
      const int ko = kq * 32 + quad * 8;
      s16x8 a0 = *(const s16x8*)&agg[sidx(wr * 32 + l16, ko)];
      s16x8 a1 = *(const s16x8*)&agg[sidx(wr * 32 + 16 + l16, ko)];
#pragma unroll
      for (int ct = 0; ct < 4; ++ct) {
        accB[0][ct] = __builtin_amdgcn_mfma_f32_16x16x32_bf16(a0, wf[ct][kq], accB[0][ct], 0, 0, 0);
        accB[1][ct] = __builtin_amdgcn_mfma_f32_16x16x32_bf16(a1, wf[ct][kq], accB[1][ct], 0, 0, 0);
      }
    }
    loadB(wt + 4 * 16384);   // w_upd2; latency overlaps epilogue+barrier
#pragma unroll
    for (int rt = 0; rt < 2; ++rt)
#pragma unroll
      for (int i = 0; i < 4; ++i) {
        const int row = wr * 32 + rt * 16 + quad * 4 + i;
#pragma unroll
        for (int ct = 0; ct < 4; ++ct) {
          const int col = wc * 64 + ct * 16 + l16;
          float v = accB[rt][ct][i] + bu1s[col];
          mbf[sidx(row, col)] = f2bf(v > 0.f ? v : 0.f);
        }
      }
  }
  __syncthreads();

  // ---- B2: h = x + (u1 @ Wu2 + bu2) -> hbf fp32 ----
  {
    f32x4 accB[2][4] = {};
#pragma unroll
    for (int kq = 0; kq < 4; ++kq) {
      const int ko = kq * 32 + quad * 8;
      s16x8 a0 = *(const s16x8*)&mbf[sidx(wr * 32 + l16, ko)];
      s16x8 a1 = *(const s16x8*)&mbf[sidx(wr * 32 + 16 + l16, ko)];
#pragma unroll
      for (int ct = 0; ct < 4; ++ct) {
        accB[0][ct] = __builtin_amdgcn_mfma_f32_16x16x32_bf16(a0, wf[ct][kq], accB[0][ct], 0, 0, 0);
        accB[1][ct] = __builtin_amdgcn_mfma_f32_16x16x32_bf16(a1, wf[ct][kq], accB[1][ct], 0, 0, 0);
      }
    }
#pragma unroll
    for (int rt = 0; rt < 2; ++rt)
#pragma unroll
      for (int i = 0; i < 4; ++i) {
        const int row = wr * 32 + rt * 16 + quad * 4 + i;
        if (row < NNODE) {
#pragma unroll
          for (int ct = 0; ct < 4; ++ct) {
            const int col = wc * 64 + ct * 16 + l16;
            hbf[row * 132 + col] = accB[rt][ct][i] + bu2s[col] + xb[row * HDIM + col];
          }
        }
      }
  }
  __syncthreads();

  // ---- LayerNorm + store ----
  for (int row = wave; row < NNODE; row += 8) {
    float2 v = *(const float2*)&hbf[row * 132 + lane * 2];
    float s1 = v.x + v.y;
    float s2 = v.x * v.x + v.y * v.y;
#pragma unroll
    for (int off = 32; off > 0; off >>= 1) {
      s1 += __shfl_xor(s1, off, 64);
      s2 += __shfl_xor(s2, off, 64);
    }
    const float mu = s1 * (1.0f / HDIM);
    const float var = s2 * (1.0f / HDIM) - mu * mu;
    const float rs = rsqrtf(var + 1e-5f);
    const int c = lane * 2;
    float2 o;
    o.x = (v.x - mu) * rs * gms[c]     + bts[c];
    o.y = (v.y - mu) * rs * gms[c + 1] + bts[c + 1];
    *(float2*)&out[((size_t)b * NNODE + row) * HDIM + c] = o;
  }
}

extern "C" void kernel_launch(void* const* d_in, const int* in_sizes, int n_in,
                              void* d_out, int out_size, void* d_ws, size_t ws_size,
                              hipStream_t stream) {
  const float* x      = (const float*)d_in[0];
  const int*   src    = (const int*)  d_in[1];
  const int*   dst    = (const int*)  d_in[2];
  const float* ed     = (const float*)d_in[3];
  const float* w_msg1 = (const float*)d_in[4];
  const float* b_msg1 = (const float*)d_in[5];
  const float* w_msg2 = (const float*)d_in[6];
  const float* b_msg2 = (const float*)d_in[7];
  const float* w_upd1 = (const float*)d_in[8];
  const float* b_upd1 = (const float*)d_in[9];
  const float* w_upd2 = (const float*)d_in[10];
  const float* b_upd2 = (const float*)d_in[11];
  const float* gamma  = (const float*)d_in[12];
  const float* beta   = (const float*)d_in[13];
  float* out = (float*)d_out;

  short* wt  = (short*)d_ws;                       // 5 * 32768 B
  int*   inl = (int*)((char*)d_ws + 163840);       // 100 * int4

  prep_kernel<<<160, NT, 0, stream>>>(w_msg1, w_msg2, w_upd1, w_upd2, dst, wt, inl);

  const int Bsz = in_sizes[0] / (NNODE * HDIM);    // 2048
  mpnn_main<<<Bsz, NT, 0, stream>>>(x, src, ed, w_msg1, b_msg1, b_msg2,
                                    b_upd1, b_upd2, gamma, beta, wt, inl, out);
}